// Round 2
// baseline (480.478 us; speedup 1.0000x reference)
//
#include <hip/hip_runtime.h>
#include <hip/hip_bf16.h>
#include <math.h>

using bf16 = __hip_bfloat16;
typedef __attribute__((ext_vector_type(8))) short bf16x8;
typedef __attribute__((ext_vector_type(4))) float f32x4;

#define B_   2
#define T_   2048
#define D_   1024
#define NH_  16
#define DH_  64
#define MLP_ 4096
#define ROWS (B_ * T_)                 // 4096
#define BHTD ((size_t)32 * 2048 * 64)  // one of Q/K/V, elements

// ---------------- weight transpose-convert: W[K][N] f32 -> Wt[N][K] bf16 ----
__global__ void wtrans_kernel(const float* __restrict__ W, bf16* __restrict__ Wt,
                              int K, int N) {
    __shared__ float tile[32][33];
    int n0 = blockIdx.x * 32, k0 = blockIdx.y * 32;
    int tx = threadIdx.x, ty = threadIdx.y;  // 32 x 8
#pragma unroll
    for (int i = 0; i < 32; i += 8)
        tile[ty + i][tx] = W[(size_t)(k0 + ty + i) * N + n0 + tx];
    __syncthreads();
#pragma unroll
    for (int i = 0; i < 32; i += 8)
        Wt[(size_t)(n0 + ty + i) * K + k0 + tx] = __float2bfloat16(tile[tx][ty + i]);
}

// ---------------- per-head V transpose: V[bh][t][64] -> Vt[bh][64][t] -------
__global__ void transpose_v_kernel(const bf16* __restrict__ V, bf16* __restrict__ Vt) {
    __shared__ bf16 tile[32][33];
    int bh = blockIdx.z;
    int t0 = blockIdx.x * 32;
    int d0 = blockIdx.y * 32;
    int tx = threadIdx.x, ty = threadIdx.y;  // 32 x 8
    const bf16* src = V + (size_t)bh * T_ * 64;
    bf16* dst = Vt + (size_t)bh * 64 * T_;
#pragma unroll
    for (int i = 0; i < 32; i += 8)
        tile[ty + i][tx] = src[(size_t)(t0 + ty + i) * 64 + d0 + tx];
    __syncthreads();
#pragma unroll
    for (int i = 0; i < 32; i += 8)
        dst[(size_t)(d0 + ty + i) * T_ + t0 + tx] = tile[tx][ty + i];
}

// ---------------- LayerNorm (row of 1024) f32 -> bf16 ----------------------
__global__ void ln_kernel(const float* __restrict__ x, const float* __restrict__ g,
                          const float* __restrict__ bta, bf16* __restrict__ out) {
    int row = blockIdx.x;
    int t = threadIdx.x;  // 256 threads * float4
    float4 v = ((const float4*)(x + (size_t)row * D_))[t];
    float s1 = v.x + v.y + v.z + v.w;
    float s2 = v.x * v.x + v.y * v.y + v.z * v.z + v.w * v.w;
#pragma unroll
    for (int m = 1; m < 64; m <<= 1) {
        s1 += __shfl_xor(s1, m);
        s2 += __shfl_xor(s2, m);
    }
    __shared__ float red[8];
    int wid = t >> 6, lane = t & 63;
    if (lane == 0) { red[wid] = s1; red[4 + wid] = s2; }
    __syncthreads();
    s1 = red[0] + red[1] + red[2] + red[3];
    s2 = red[4] + red[5] + red[6] + red[7];
    float mu = s1 * (1.0f / D_);
    float var = s2 * (1.0f / D_) - mu * mu;
    float rs = rsqrtf(var + 1e-5f);
    float4 gv = ((const float4*)g)[t];
    float4 bv = ((const float4*)bta)[t];
    bf16* o = out + (size_t)row * D_ + t * 4;
    o[0] = __float2bfloat16((v.x - mu) * rs * gv.x + bv.x);
    o[1] = __float2bfloat16((v.y - mu) * rs * gv.y + bv.y);
    o[2] = __float2bfloat16((v.z - mu) * rs * gv.z + bv.z);
    o[3] = __float2bfloat16((v.w - mu) * rs * gv.w + bv.w);
}

// ---------------- GEMM: C[M][N] = A[M][K](bf16) @ Bt[N][K](bf16)^T ----------
// 128x128 tile, BK=64, 256 threads = 2x2 waves, each wave 64x64 (4x4 frags).
// EPI 0: qkv head-scatter (bf16).  EPI 1: +bias +resid -> f32.
// EPI 2: gelu(+bias) -> bf16.
template <int EPI>
__global__ __launch_bounds__(256) void gemm_bt(const bf16* __restrict__ A,
                                               const bf16* __restrict__ Bt,
                                               int N, int K,
                                               const float* __restrict__ bias,
                                               const float* __restrict__ resid,
                                               void* __restrict__ out) {
    __shared__ __align__(16) bf16 Asm[128][72];  // +8 pad: 144B stride, 16B aligned
    __shared__ __align__(16) bf16 Bsm[128][72];
    int tid = threadIdx.x;
    int bm = blockIdx.y * 128;
    int bn = blockIdx.x * 128;
    int wid = tid >> 6, lane = tid & 63;
    int wr = wid >> 1, wc = wid & 1;
    f32x4 acc[4][4];
#pragma unroll
    for (int m = 0; m < 4; m++)
#pragma unroll
        for (int n = 0; n < 4; n++) acc[m][n] = (f32x4){0.f, 0.f, 0.f, 0.f};

    for (int k0 = 0; k0 < K; k0 += 64) {
        __syncthreads();
#pragma unroll
        for (int i = 0; i < 4; i++) {
            int c = tid + i * 256;
            int row = c >> 3, col8 = (c & 7) * 8;
            *(uint4*)&Asm[row][col8] = *(const uint4*)&A[(size_t)(bm + row) * K + k0 + col8];
            *(uint4*)&Bsm[row][col8] = *(const uint4*)&Bt[(size_t)(bn + row) * K + k0 + col8];
        }
        __syncthreads();
#pragma unroll
        for (int kk = 0; kk < 2; kk++) {
            bf16x8 af[4], bfr[4];
#pragma unroll
            for (int m = 0; m < 4; m++)
                af[m] = *(const bf16x8*)&Asm[wr * 64 + m * 16 + (lane & 15)][kk * 32 + (lane >> 4) * 8];
#pragma unroll
            for (int n = 0; n < 4; n++)
                bfr[n] = *(const bf16x8*)&Bsm[wc * 64 + n * 16 + (lane & 15)][kk * 32 + (lane >> 4) * 8];
#pragma unroll
            for (int m = 0; m < 4; m++)
#pragma unroll
                for (int n = 0; n < 4; n++)
                    acc[m][n] = __builtin_amdgcn_mfma_f32_16x16x32_bf16(af[m], bfr[n], acc[m][n], 0, 0, 0);
        }
    }
    int r0 = bm + wr * 64;
    int c0 = bn + wc * 64;
#pragma unroll
    for (int m = 0; m < 4; m++) {
#pragma unroll
        for (int n = 0; n < 4; n++) {
#pragma unroll
            for (int j = 0; j < 4; j++) {
                int r = r0 + m * 16 + (lane >> 4) * 4 + j;
                int c = c0 + n * 16 + (lane & 15);
                float v = acc[m][n][j];
                if constexpr (EPI == 0) {
                    int which = c >> 10, d = c & 1023;
                    int h = d >> 6, dh = d & 63;
                    int b = r >> 11, t = r & 2047;
                    ((bf16*)out)[(((size_t)which * 32 + b * 16 + h) * 2048 + t) * 64 + dh] =
                        __float2bfloat16(v);
                } else if constexpr (EPI == 1) {
                    ((float*)out)[(size_t)r * N + c] = v + bias[c] + resid[(size_t)r * N + c];
                } else {
                    float u = v + bias[c];
                    float ge = 0.5f * u * (1.0f + erff(u * 0.70710678118f));
                    ((bf16*)out)[(size_t)r * N + c] = __float2bfloat16(ge);
                }
            }
        }
    }
}

// ---------------- flash attention: per (bh, 64-q-row tile) ------------------
__global__ __launch_bounds__(256) void attn_kernel(const bf16* __restrict__ Q,
                                                   const bf16* __restrict__ Kt,
                                                   const bf16* __restrict__ Vt,
                                                   bf16* __restrict__ Y) {
    __shared__ __align__(16) bf16 Ksm[64][72];
    __shared__ __align__(16) bf16 Vsm[64][72];       // Vsm[dh][key]
    __shared__ __align__(16) bf16 Psm[4][16][72];    // per-wave P[q][key]
    int tid = threadIdx.x;
    int wid = tid >> 6, lane = tid & 63;
    int bh = blockIdx.y;
    int q0 = blockIdx.x * 64 + wid * 16;
    const bf16* Qb = Q + (size_t)bh * T_ * 64;
    const bf16* Kb = Kt + (size_t)bh * T_ * 64;
    const bf16* Vb = Vt + (size_t)bh * 64 * T_;

    bf16x8 aq[2];
#pragma unroll
    for (int kk = 0; kk < 2; kk++)
        aq[kk] = *(const bf16x8*)&Qb[(size_t)(q0 + (lane & 15)) * 64 + kk * 32 + (lane >> 4) * 8];

    float mrow[4], lrow[4];
    f32x4 o[4];
#pragma unroll
    for (int j = 0; j < 4; j++) { mrow[j] = -1e30f; lrow[j] = 0.f; }
#pragma unroll
    for (int n = 0; n < 4; n++) o[n] = (f32x4){0.f, 0.f, 0.f, 0.f};

    for (int kt = 0; kt < T_ / 64; kt++) {
        __syncthreads();
#pragma unroll
        for (int i = 0; i < 2; i++) {
            int c = tid + i * 256;
            int row = c >> 3, col8 = (c & 7) * 8;
            *(uint4*)&Ksm[row][col8] = *(const uint4*)&Kb[(size_t)(kt * 64 + row) * 64 + col8];
            *(uint4*)&Vsm[row][col8] = *(const uint4*)&Vb[(size_t)row * T_ + kt * 64 + col8];
        }
        __syncthreads();

        f32x4 s[4];
#pragma unroll
        for (int n = 0; n < 4; n++) {
            bf16x8 b0 = *(const bf16x8*)&Ksm[n * 16 + (lane & 15)][(lane >> 4) * 8];
            bf16x8 b1 = *(const bf16x8*)&Ksm[n * 16 + (lane & 15)][32 + (lane >> 4) * 8];
            s[n] = __builtin_amdgcn_mfma_f32_16x16x32_bf16(aq[0], b0, (f32x4){0.f, 0.f, 0.f, 0.f}, 0, 0, 0);
            s[n] = __builtin_amdgcn_mfma_f32_16x16x32_bf16(aq[1], b1, s[n], 0, 0, 0);
        }
#pragma unroll
        for (int n = 0; n < 4; n++) s[n] *= 0.125f;

        float mnew[4], sc[4];
#pragma unroll
        for (int j = 0; j < 4; j++) {
            float mj = fmaxf(fmaxf(s[0][j], s[1][j]), fmaxf(s[2][j], s[3][j]));
            mj = fmaxf(mj, __shfl_xor(mj, 1));
            mj = fmaxf(mj, __shfl_xor(mj, 2));
            mj = fmaxf(mj, __shfl_xor(mj, 4));
            mj = fmaxf(mj, __shfl_xor(mj, 8));
            float mn = fmaxf(mrow[j], mj);
            sc[j] = __expf(mrow[j] - mn);
            mnew[j] = mn;
            mrow[j] = mn;
        }
        float psum[4] = {0.f, 0.f, 0.f, 0.f};
#pragma unroll
        for (int n = 0; n < 4; n++)
#pragma unroll
            for (int j = 0; j < 4; j++) {
                float pv = __expf(s[n][j] - mnew[j]);
                s[n][j] = pv;
                psum[j] += pv;
            }
#pragma unroll
        for (int j = 0; j < 4; j++) {
            psum[j] += __shfl_xor(psum[j], 1);
            psum[j] += __shfl_xor(psum[j], 2);
            psum[j] += __shfl_xor(psum[j], 4);
            psum[j] += __shfl_xor(psum[j], 8);
            lrow[j] = lrow[j] * sc[j] + psum[j];
        }
#pragma unroll
        for (int n = 0; n < 4; n++)
#pragma unroll
            for (int j = 0; j < 4; j++) o[n][j] *= sc[j];

        // P -> LDS (per-wave) -> A-frags
#pragma unroll
        for (int n = 0; n < 4; n++)
#pragma unroll
            for (int j = 0; j < 4; j++)
                Psm[wid][(lane >> 4) * 4 + j][n * 16 + (lane & 15)] = __float2bfloat16(s[n][j]);

        bf16x8 pa[2];
#pragma unroll
        for (int kk = 0; kk < 2; kk++)
            pa[kk] = *(const bf16x8*)&Psm[wid][lane & 15][kk * 32 + (lane >> 4) * 8];

#pragma unroll
        for (int n = 0; n < 4; n++) {
            bf16x8 v0 = *(const bf16x8*)&Vsm[n * 16 + (lane & 15)][(lane >> 4) * 8];
            bf16x8 v1 = *(const bf16x8*)&Vsm[n * 16 + (lane & 15)][32 + (lane >> 4) * 8];
            o[n] = __builtin_amdgcn_mfma_f32_16x16x32_bf16(pa[0], v0, o[n], 0, 0, 0);
            o[n] = __builtin_amdgcn_mfma_f32_16x16x32_bf16(pa[1], v1, o[n], 0, 0, 0);
        }
    }

    int b = bh >> 4, h = bh & 15;
#pragma unroll
    for (int j = 0; j < 4; j++) {
        float inv = 1.0f / lrow[j];
        int t = q0 + (lane >> 4) * 4 + j;
#pragma unroll
        for (int n = 0; n < 4; n++) {
            int c = h * 64 + n * 16 + (lane & 15);
            Y[((size_t)b * T_ + t) * D_ + c] = __float2bfloat16(o[n][j] * inv);
        }
    }
}

// ---------------------------------------------------------------------------
extern "C" void kernel_launch(void* const* d_in, const int* in_sizes, int n_in,
                              void* d_out, int out_size, void* d_ws, size_t ws_size,
                              hipStream_t stream) {
    const float* inputs = (const float*)d_in[0];
    // d_in[1] cond, d_in[2] attention_mask: unused by reference path
    const float* ln1_g = (const float*)d_in[3];
    const float* ln1_b = (const float*)d_in[4];
    const float* ln2_g = (const float*)d_in[5];
    const float* ln2_b = (const float*)d_in[6];
    const float* w_qkv = (const float*)d_in[7];
    const float* w_out = (const float*)d_in[8];
    const float* b_out = (const float*)d_in[9];
    const float* w1    = (const float*)d_in[10];
    const float* b1    = (const float*)d_in[11];
    const float* w2    = (const float*)d_in[12];
    const float* b2    = (const float*)d_in[13];

    char* p = (char*)d_ws;
    auto alloc = [&](size_t bytes) {
        void* r = (void*)p;
        p += (bytes + 255) & ~(size_t)255;
        return r;
    };
    bf16* x1     = (bf16*)alloc((size_t)ROWS * D_ * 2);
    bf16* wqkv_t = (bf16*)alloc((size_t)3 * D_ * D_ * 2);
    bf16* wout_t = (bf16*)alloc((size_t)D_ * D_ * 2);
    bf16* w1_t   = (bf16*)alloc((size_t)MLP_ * D_ * 2);
    bf16* w2_t   = (bf16*)alloc((size_t)D_ * MLP_ * 2);
    bf16* qkv    = (bf16*)alloc((size_t)3 * BHTD * 2);
    bf16* vt     = (bf16*)alloc((size_t)BHTD * 2);
    bf16* y      = (bf16*)alloc((size_t)ROWS * D_ * 2);
    float* x2    = (float*)alloc((size_t)ROWS * D_ * 4);
    bf16* h2     = (bf16*)alloc((size_t)ROWS * D_ * 2);
    bf16* act    = (bf16*)alloc((size_t)ROWS * MLP_ * 2);

    dim3 tb(32, 8);
    wtrans_kernel<<<dim3(3 * D_ / 32, D_ / 32), tb, 0, stream>>>(w_qkv, wqkv_t, D_, 3 * D_);
    wtrans_kernel<<<dim3(D_ / 32, D_ / 32), tb, 0, stream>>>(w_out, wout_t, D_, D_);
    wtrans_kernel<<<dim3(MLP_ / 32, D_ / 32), tb, 0, stream>>>(w1, w1_t, D_, MLP_);
    wtrans_kernel<<<dim3(D_ / 32, MLP_ / 32), tb, 0, stream>>>(w2, w2_t, MLP_, D_);

    ln_kernel<<<ROWS, 256, 0, stream>>>(inputs, ln1_g, ln1_b, x1);

    gemm_bt<0><<<dim3(3 * D_ / 128, ROWS / 128), 256, 0, stream>>>(
        x1, wqkv_t, 3 * D_, D_, nullptr, nullptr, (void*)qkv);

    transpose_v_kernel<<<dim3(T_ / 32, 2, 32), tb, 0, stream>>>(qkv + 2 * BHTD, vt);

    attn_kernel<<<dim3(T_ / 64, 32), 256, 0, stream>>>(qkv, qkv + BHTD, vt, y);

    gemm_bt<1><<<dim3(D_ / 128, ROWS / 128), 256, 0, stream>>>(
        y, wout_t, D_, D_, b_out, inputs, (void*)x2);

    ln_kernel<<<ROWS, 256, 0, stream>>>(x2, ln2_g, ln2_b, h2);

    gemm_bt<2><<<dim3(MLP_ / 128, ROWS / 128), 256, 0, stream>>>(
        h2, w1_t, MLP_, D_, b1, nullptr, (void*)act);

    gemm_bt<1><<<dim3(D_ / 128, ROWS / 128), 256, 0, stream>>>(
        act, w2_t, D_, MLP_, b2, x2, d_out);
}